// Round 7
// baseline (594.491 us; speedup 1.0000x reference)
//
#include <hip/hip_runtime.h>
#include <cstdint>
#include <cstddef>

// ---------------------------------------------------------------------------
// JambaMambaBlock on MI355X (gfx950)
// Pipeline: rmsnorm -> GEMM1(in_proj, split epilogue: x fp32 / silu(z) bf16)
//           -> depthwise conv+silu -> GEMM2(x_proj, softplus epilogue)
//           -> chunked SSM scan (3 phases) -> GEMM3(out_proj, +residual)
//
// GEMMs (round 7): barrier-free direct-global K-loop on fragment-linear
// operands (validated round 6), with 2-wave blocks and 64x128 per-wave tiles
// (round 6 showed the 64x64-wave version is L1/L2-BW-bound at 63 TB/s
// issued: intensity 32 -> 42.7 cuts issued traffic by 25% and shares the
// whole B set between the block's 2 waves).
// Producers write swizzled layout with coalesced stores (round-6 regression
// fix): conv = wave-per-tile, rmsnorm = LDS-staged.
// Scan: 32 chunks of 64 steps; 4 lanes per d-channel; depth-4 reg prefetch.
// ---------------------------------------------------------------------------

typedef __bf16 bf16_t;
typedef __attribute__((ext_vector_type(8))) __bf16 bf16x8;
typedef __attribute__((ext_vector_type(4))) __bf16 bf16x4;
typedef __attribute__((ext_vector_type(4))) float f32x4;

#define D_MODEL 2048
#define D_STATE 16
#define B_SZ 2
#define T_LEN 2048
#define N_ROWS (B_SZ * T_LEN)        // 4096
#define N_PAD  2176                  // x_proj rows padded 2080 -> 17*128
#define N_CHUNK 32
#define L_CHUNK (T_LEN / N_CHUNK)    // 64
#define LOG2E 1.4426950408889634f
#define KT 64                        // K=2048 -> 64 k-tiles everywhere
#define PANEL 32768                  // 64 tiles * 512 elems per 16-row panel

// ---------------- fused weight cast + swizzle ----------------
// tiles: W1 16384 | W2 8704 (rows >=2080 zero) | W3 8192; one wave per tile
__global__ __launch_bounds__(256) void cast_weights(
    const float* __restrict__ w_in, const float* __restrict__ w_x,
    const float* __restrict__ w_out,
    bf16_t* __restrict__ W1s, bf16_t* __restrict__ W2s, bf16_t* __restrict__ W3s)
{
    int wv   = blockIdx.x * 4 + (threadIdx.x >> 6);
    int lane = threadIdx.x & 63;
    const float* src; bf16_t* dst; int nrows; int tile;
    if (wv < 16384)      { src = w_in;  dst = W1s; tile = wv;         nrows = 4096; }
    else if (wv < 25088) { src = w_x;   dst = W2s; tile = wv - 16384; nrows = 2080; }
    else                 { src = w_out; dst = W3s; tile = wv - 25088; nrows = 2048; }
    int r16 = tile >> 6, kt = tile & 63;
    int row = r16 * 16 + (lane & 15);
    int k0  = kt * 32 + (lane >> 4) * 8;
    f32x4 v0 = {0.f, 0.f, 0.f, 0.f}, v1 = v0;
    if (row < nrows) {
        v0 = *(const f32x4*)&src[(size_t)row * 2048 + k0];
        v1 = *(const f32x4*)&src[(size_t)row * 2048 + k0 + 4];
    }
    bf16x4 lo = __builtin_convertvector(v0, bf16x4);
    bf16x4 hi = __builtin_convertvector(v1, bf16x4);
    bf16x8 o;
    #pragma unroll
    for (int e = 0; e < 4; ++e) { o[e] = lo[e]; o[e + 4] = hi[e]; }
    *(bf16x8*)(dst + (size_t)tile * 512 + lane * 8) = o;
}

// ---------------- rmsnorm -> swizzled bf16 (LDS-staged) ----------------
// one block per 16-row panel: coalesced row reads -> LDS -> coalesced
// swizzled 16B stores.
__global__ __launch_bounds__(256) void rmsnorm_swz(
    const float* __restrict__ x, const float* __restrict__ w,
    bf16_t* __restrict__ xn)
{
    __shared__ bf16_t st[16][2056];           // +8 pad breaks bank stride
    int r16 = blockIdx.x;                     // 0..255
    int tid = threadIdx.x;
    int wave = tid >> 6, lane = tid & 63;

    f32x4 wv[8];
    #pragma unroll
    for (int c = 0; c < 8; ++c) wv[c] = *(const f32x4*)&w[(c * 64 + lane) * 4];

    for (int rr = 0; rr < 4; ++rr) {
        int row = r16 * 16 + wave * 4 + rr;
        const float* xr = x + (size_t)row * 2048;
        f32x4 vv[8];
        float ss = 0.f;
        #pragma unroll
        for (int c = 0; c < 8; ++c) {
            vv[c] = *(const f32x4*)&xr[(c * 64 + lane) * 4];
            ss += vv[c][0]*vv[c][0] + vv[c][1]*vv[c][1]
                + vv[c][2]*vv[c][2] + vv[c][3]*vv[c][3];
        }
        #pragma unroll
        for (int o = 32; o > 0; o >>= 1) ss += __shfl_down(ss, o, 64);
        float s = __shfl(ss, 0, 64);
        s = rsqrtf(s * (1.f / 2048.f) + 1e-6f);
        #pragma unroll
        for (int c = 0; c < 8; ++c) {
            bf16x4 o4;
            #pragma unroll
            for (int e = 0; e < 4; ++e) o4[e] = (bf16_t)(vv[c][e] * s * wv[c][e]);
            *(bf16x4*)&st[wave * 4 + rr][(c * 64 + lane) * 4] = o4;
        }
    }
    __syncthreads();
    const size_t base = (size_t)r16 * PANEL;
    #pragma unroll
    for (int c = 0; c < 16; ++c) {
        int f  = (c * 256 + tid) * 8;         // swizzled flat element offset
        int kt = f >> 9;
        int off3 = (f & 511) >> 3;            // m + 16*q
        int m = off3 & 15, q = off3 >> 4;
        bf16x8 v = *(const bf16x8*)&st[m][kt * 32 + q * 8];
        *(bf16x8*)(xn + base + f) = v;
    }
}

// ---------------- bf16 GEMM: C[M,N] = A @ B^T, fragment-direct ----------
// 128 threads = 2 waves; block tile 128x128; wave tile 64x128 (4 A-panels,
// 8 B-panels shared by both waves). K = 2048 (KT=64).
// MODE 0 (GEMM1): bn<16 -> out0 fp32 ldc 2048; bn>=16 -> out1 bf16 silu
// MODE 1 (GEMM2): out0 fp32 ldc N_PAD; softplus when bn<16
// MODE 2 (GEMM3): out0 = v + add, fp32 ldc 2048
template<int MODE>
__global__ __launch_bounds__(128) void gemm_bt(
    const bf16_t* __restrict__ A, const bf16_t* __restrict__ B,
    float* __restrict__ out0, bf16_t* __restrict__ out1,
    const float* __restrict__ add)
{
    __shared__ __align__(16) float cs[2][16 * 132];   // per-wave epilogue strip
    const int tid = threadIdx.x;
    const int bm = blockIdx.x, bn = blockIdx.y;
    const int lane = tid & 63;
    const int wave = tid >> 6;        // M-half
    const int fr = lane & 15;
    const int quad = lane >> 4;

    const bf16_t* aB = A + (((size_t)(bm * 8 + wave * 4) * KT) << 9) + lane * 8;
    const bf16_t* bB = B + (((size_t)(bn * 8) * KT) << 9) + lane * 8;

    f32x4 acc[4][8];
    #pragma unroll
    for (int i = 0; i < 4; ++i)
        #pragma unroll
        for (int j = 0; j < 8; ++j) acc[i][j] = {0.f, 0.f, 0.f, 0.f};

    bf16x8 aC[4], bC[8];
    #pragma unroll
    for (int i = 0; i < 4; ++i) aC[i] = *(const bf16x8*)(aB + (size_t)i * PANEL);
    #pragma unroll
    for (int j = 0; j < 8; ++j) bC[j] = *(const bf16x8*)(bB + (size_t)j * PANEL);

    #pragma unroll 2
    for (int kt = 0; kt < KT; ++kt) {
        const int ktn = (kt < KT - 1) ? (kt + 1) : (KT - 1);
        bf16x8 aN[4], bN[8];
        #pragma unroll
        for (int i = 0; i < 4; ++i)
            aN[i] = *(const bf16x8*)(aB + (size_t)i * PANEL + ((size_t)ktn << 9));
        #pragma unroll
        for (int j = 0; j < 8; ++j)
            bN[j] = *(const bf16x8*)(bB + (size_t)j * PANEL + ((size_t)ktn << 9));
        #pragma unroll
        for (int i = 0; i < 4; ++i)
            #pragma unroll
            for (int j = 0; j < 8; ++j)
                acc[i][j] = __builtin_amdgcn_mfma_f32_16x16x32_bf16(
                    aC[i], bC[j], acc[i][j], 0, 0, 0);
        #pragma unroll
        for (int i = 0; i < 4; ++i) aC[i] = aN[i];
        #pragma unroll
        for (int j = 0; j < 8; ++j) bC[j] = bN[j];
    }

    // ---- per-wave LDS strip epilogue (no cross-wave barrier needed) ----
    float* csw = cs[wave];
    for (int i = 0; i < 4; ++i) {              // 16-row strips
        #pragma unroll
        for (int j = 0; j < 8; ++j)
            #pragma unroll
            for (int rr = 0; rr < 4; ++rr)
                csw[(quad * 4 + rr) * 132 + j * 16 + fr] = acc[i][j][rr];
        #pragma unroll
        for (int s = 0; s < 8; ++s) {
            int t   = lane + s * 64;           // 0..511 f32x4 chunks
            int row = t >> 5;
            int c4  = (t & 31) * 4;
            f32x4 v = *(const f32x4*)&csw[row * 132 + c4];
            int gr = bm * 128 + wave * 64 + i * 16 + row;
            int gc = bn * 128 + c4;
            if (MODE == 0) {
                if (bn < 16) {
                    *(f32x4*)&out0[(size_t)gr * 2048 + gc] = v;
                } else {
                    bf16x4 o;
                    #pragma unroll
                    for (int e = 0; e < 4; ++e) {
                        float sv = v[e];
                        o[e] = (bf16_t)(sv / (1.f + __expf(-sv)));
                    }
                    *(bf16x4*)&out1[(size_t)gr * 2048 + (gc - 2048)] = o;
                }
            } else if (MODE == 1) {
                if (bn < 16) {
                    #pragma unroll
                    for (int e = 0; e < 4; ++e) {
                        float sv = v[e];
                        v[e] = fmaxf(sv, 0.f) + __logf(1.f + __expf(-fabsf(sv)));
                    }
                }
                *(f32x4*)&out0[(size_t)gr * N_PAD + gc] = v;
            } else {
                f32x4 a4 = *(const f32x4*)&add[(size_t)gr * 2048 + gc];
                v = v + a4;
                *(f32x4*)&out0[(size_t)gr * 2048 + gc] = v;
            }
        }
    }
}

// ---------------- depthwise causal conv(4) + silu -> swizzled bf16 --------
// wave-per-tile: each wave emits one complete 1KB tile (16 t x 32 d) with a
// single fully-coalesced 16B/lane store.
__global__ __launch_bounds__(256) void conv_silu_swz(
    const float* __restrict__ xb, const float* __restrict__ cw,
    const float* __restrict__ cb, bf16_t* __restrict__ xs_s)
{
    int tile = blockIdx.x * 4 + (threadIdx.x >> 6);   // 0..16383
    int lane = threadIdx.x & 63;
    int r16  = tile >> 6;                // 16-row group (0..255)
    int dt   = tile & 63;                // d-tile
    int m    = lane & 15;
    int d0   = dt * 32 + (lane >> 4) * 8;
    int row  = r16 * 16 + m;
    int t    = row & 2047;               // t within batch

    float a[8];
    {
        f32x4 b0 = *(const f32x4*)&cb[d0], b1 = *(const f32x4*)&cb[d0 + 4];
        #pragma unroll
        for (int e = 0; e < 4; ++e) { a[e] = b0[e]; a[4 + e] = b1[e]; }
    }
    f32x4 cwv[8];
    #pragma unroll
    for (int e = 0; e < 8; ++e) cwv[e] = *(const f32x4*)&cw[(d0 + e) * 4];

    #pragma unroll
    for (int tap = 0; tap < 4; ++tap) {
        int tr = t - 3 + tap;
        if (tr >= 0) {
            const float* xr = xb + ((size_t)(row - 3 + tap)) * 2048 + d0;
            f32x4 x0 = *(const f32x4*)xr, x1 = *(const f32x4*)(xr + 4);
            #pragma unroll
            for (int e = 0; e < 4; ++e) {
                a[e]     = fmaf(cwv[e][tap],     x0[e], a[e]);
                a[4 + e] = fmaf(cwv[4 + e][tap], x1[e], a[4 + e]);
            }
        }
    }
    bf16x8 o;
    #pragma unroll
    for (int e = 0; e < 8; ++e) {
        float s = a[e];
        o[e] = (bf16_t)(s / (1.f + __expf(-s)));
    }
    *(bf16x8*)(xs_s + (size_t)tile * 512 + lane * 8) = o;
}

// ---------------- chunked SSM scan ----------------
// Wave wi in [0,8192): c = wi&31, dg = (wi>>5)&127, b = wi>>12.
// Lane: nq = lane&3 (state quad), dsub = lane>>2; dd = dg*16 + dsub.
// xs is fragment-swizzled bf16; proj is row-major fp32 (da|B|C), pitch N_PAD.
#define PF 4   // prefetch depth

__device__ __forceinline__ size_t xs_off(int row, int ddo) {
    return ((size_t)(row >> 4) << 15) + (size_t)((row & 15) << 3) + ddo;
}

// phase 1: local scan with zero init; store decay product + local final state
__global__ __launch_bounds__(256) void scan_phase1(
    const float* __restrict__ proj, const bf16_t* __restrict__ xs,
    const float* __restrict__ A_log,
    float* __restrict__ Aprod, float* __restrict__ hfin)
{
    int wi   = blockIdx.x * 4 + (threadIdx.x >> 6);
    int lane = threadIdx.x & 63;
    int nq   = lane & 3;
    int dsub = lane >> 2;
    int c  = wi & 31;
    int dg = (wi >> 5) & 127;
    int b  = wi >> 12;
    int dd = dg * 16 + dsub;
    const int ddo = ((dd >> 5) << 9) + (((dd & 31) >> 3) << 7) + (dd & 7);

    float A2[4], h[4], Ap[4];
    #pragma unroll
    for (int j = 0; j < 4; ++j) {
        A2[j] = -__expf(A_log[dd * D_STATE + nq * 4 + j]) * LOG2E;
        h[j] = 0.f; Ap[j] = 1.f;
    }
    const int t0 = c * L_CHUNK;
    const int tmax = t0 + L_CHUNK - 1;

    float p_da[PF], p_xv[PF];
    f32x4 p_B[PF];
    #pragma unroll
    for (int u = 0; u < PF; ++u) {
        int row = b * T_LEN + t0 + u;
        const float* pr = proj + (size_t)row * N_PAD;
        p_da[u] = pr[dd];
        p_xv[u] = (float)xs[xs_off(row, ddo)];
        p_B[u]  = *(const f32x4*)(pr + D_MODEL + nq * 4);
    }

    for (int it = 0; it < L_CHUNK; it += PF) {
        #pragma unroll
        for (int u = 0; u < PF; ++u) {
            int t = t0 + it + u;
            float da = p_da[u], xv = p_xv[u];
            f32x4 Bv = p_B[u];
            int tn = t + PF; tn = (tn > tmax) ? tmax : tn;
            {
                int row = b * T_LEN + tn;
                const float* pr = proj + (size_t)row * N_PAD;
                p_da[u] = pr[dd];
                p_xv[u] = (float)xs[xs_off(row, ddo)];
                p_B[u]  = *(const f32x4*)(pr + D_MODEL + nq * 4);
            }
            float dx = da * xv;
            #pragma unroll
            for (int j = 0; j < 4; ++j) {
                float a = exp2f(da * A2[j]);
                Ap[j] *= a;
                h[j] = fmaf(a, h[j], dx * Bv[j]);
            }
        }
    }
    size_t o = ((size_t)c * 4096 + b * 2048 + dd) * D_STATE + nq * 4;
    *(f32x4*)(Aprod + o) = f32x4{Ap[0], Ap[1], Ap[2], Ap[3]};
    *(f32x4*)(hfin  + o) = f32x4{h[0], h[1], h[2], h[3]};
}

// phase 2: serial combine across chunks; hfin -> h_init in place; h_out exact
__global__ __launch_bounds__(256) void scan_phase2(
    const float* __restrict__ h_in, const float* __restrict__ Aprod,
    float* __restrict__ hfin, float* __restrict__ h_out)
{
    int g = blockIdx.x * 256 + threadIdx.x;
    float h = h_in[g];
    for (int c = 0; c < N_CHUNK; ++c) {
        size_t o = (size_t)c * 65536 + g;
        float a   = Aprod[o];
        float loc = hfin[o];
        hfin[o] = h;
        h = fmaf(a, h, loc);
    }
    h_out[g] = h;
}

// phase 3: replay from exact initial state; emit gated y (swizzled bf16)
__global__ __launch_bounds__(256) void scan_phase3(
    const float* __restrict__ proj, const bf16_t* __restrict__ xs,
    const bf16_t* __restrict__ zg, const float* __restrict__ A_log,
    const float* __restrict__ Dv, const float* __restrict__ hinit,
    bf16_t* __restrict__ yg)
{
    int wi   = blockIdx.x * 4 + (threadIdx.x >> 6);
    int lane = threadIdx.x & 63;
    int nq   = lane & 3;
    int dsub = lane >> 2;
    int c  = wi & 31;
    int dg = (wi >> 5) & 127;
    int b  = wi >> 12;
    int dd = dg * 16 + dsub;
    const int ddo = ((dd >> 5) << 9) + (((dd & 31) >> 3) << 7) + (dd & 7);

    float A2[4], h[4];
    size_t o = ((size_t)c * 4096 + b * 2048 + dd) * D_STATE + nq * 4;
    #pragma unroll
    for (int j = 0; j < 4; ++j) {
        A2[j] = -__expf(A_log[dd * D_STATE + nq * 4 + j]) * LOG2E;
        h[j]  = hinit[o + j];
    }
    float Dd = Dv[dd];
    const int t0 = c * L_CHUNK;
    const int tmax = t0 + L_CHUNK - 1;

    float p_da[PF], p_xv[PF], p_sz[PF];
    f32x4 p_B[PF], p_C[PF];
    #pragma unroll
    for (int u = 0; u < PF; ++u) {
        int row = b * T_LEN + t0 + u;
        const float* pr = proj + (size_t)row * N_PAD;
        p_da[u] = pr[dd];
        p_xv[u] = (float)xs[xs_off(row, ddo)];
        p_sz[u] = (float)zg[(size_t)row * 2048 + dd];
        p_B[u]  = *(const f32x4*)(pr + D_MODEL + nq * 4);
        p_C[u]  = *(const f32x4*)(pr + D_MODEL + D_STATE + nq * 4);
    }

    for (int it = 0; it < L_CHUNK; it += PF) {
        #pragma unroll
        for (int u = 0; u < PF; ++u) {
            int t = t0 + it + u;
            float da = p_da[u], xv = p_xv[u], sz = p_sz[u];
            f32x4 Bv = p_B[u], Cv = p_C[u];
            int tn = t + PF; tn = (tn > tmax) ? tmax : tn;
            {
                int row = b * T_LEN + tn;
                const float* pr = proj + (size_t)row * N_PAD;
                p_da[u] = pr[dd];
                p_xv[u] = (float)xs[xs_off(row, ddo)];
                p_sz[u] = (float)zg[(size_t)row * 2048 + dd];
                p_B[u]  = *(const f32x4*)(pr + D_MODEL + nq * 4);
                p_C[u]  = *(const f32x4*)(pr + D_MODEL + D_STATE + nq * 4);
            }
            float dx = da * xv;
            float yp = 0.f;
            #pragma unroll
            for (int j = 0; j < 4; ++j) {
                float a = exp2f(da * A2[j]);
                h[j] = fmaf(a, h[j], dx * Bv[j]);
                yp = fmaf(h[j], Cv[j], yp);
            }
            yp += __shfl_xor(yp, 1, 64);
            yp += __shfl_xor(yp, 2, 64);
            if (nq == 0) {
                float y = fmaf(Dd, xv, yp);
                int row = b * T_LEN + t;
                yg[xs_off(row, ddo)] = (bf16_t)(y * sz);
            }
        }
    }
}

// ---------------------------------------------------------------------------
extern "C" void kernel_launch(void* const* d_in, const int* in_sizes, int n_in,
                              void* d_out, int out_size, void* d_ws, size_t ws_size,
                              hipStream_t stream)
{
    const float* x    = (const float*)d_in[0];
    const float* h0   = (const float*)d_in[1];
    const float* nw   = (const float*)d_in[2];
    const float* w_in = (const float*)d_in[3];
    const float* cw   = (const float*)d_in[4];
    const float* cb   = (const float*)d_in[5];
    const float* w_x  = (const float*)d_in[6];
    const float* alog = (const float*)d_in[7];
    const float* dv   = (const float*)d_in[8];
    const float* w_out= (const float*)d_in[9];
    float* out  = (float*)d_out;
    float* hout = out + (size_t)N_ROWS * D_MODEL;

    char* ws = (char*)d_ws;
    size_t off = 0;
    auto alloc = [&](size_t bytes) -> void* {
        void* p = ws + off;
        off += (bytes + 255) & ~(size_t)255;
        return p;
    };
    bf16_t* W1  = (bf16_t*)alloc((size_t)16384 * 512 * 2);   // in_proj swizzled
    bf16_t* W2  = (bf16_t*)alloc((size_t)8704 * 512 * 2);    // x_proj swizzled+pad
    bf16_t* W3  = (bf16_t*)alloc((size_t)8192 * 512 * 2);    // out_proj swizzled
    bf16_t* XN  = (bf16_t*)alloc((size_t)N_ROWS * 2048 * 2); // normed x, swizzled
    float*  XB  = (float*) alloc((size_t)N_ROWS * 2048 * 4); // x-branch fp32 rm
    bf16_t* ZG  = (bf16_t*)alloc((size_t)N_ROWS * 2048 * 2); // silu(z) bf16 rm
    float*  PROJ= (float*) alloc((size_t)N_ROWS * N_PAD * 4);// da|B|C fp32 rm
    float* APROD= (float*) alloc((size_t)N_CHUNK * 4096 * D_STATE * 4);
    float* HFIN = (float*) alloc((size_t)N_CHUNK * 4096 * D_STATE * 4);
    // aliases (lifetimes disjoint in stream order):
    bf16_t* XSb = W1;   // conv out, swizzled (W1 dead after GEMM1; lives thru scan)
    bf16_t* YG  = XN;   // gated y, swizzled  (XN dead after GEMM1)

    // weight casts + swizzle (33280 tiles, 4 waves/block)
    cast_weights<<<8320, 256, 0, stream>>>(w_in, w_x, w_out, W1, W2, W3);

    // 1) rmsnorm -> swizzled XN (LDS-staged coalesced)
    rmsnorm_swz<<<256, 256, 0, stream>>>(x, nw, XN);
    // 2) xz = xn @ W_in^T; epilogue splits x fp32 / silu(z) bf16
    gemm_bt<0><<<dim3(32, 32), 128, 0, stream>>>(XN, W1, XB, ZG, nullptr);
    // 3) conv + silu -> swizzled bf16 (wave-per-tile, coalesced stores)
    conv_silu_swz<<<4096, 256, 0, stream>>>(XB, cw, cb, XSb);
    // 4) proj = xssm @ W_x^T; epilogue applies softplus to delta cols
    gemm_bt<1><<<dim3(32, 17), 128, 0, stream>>>(XSb, W2, PROJ, nullptr, nullptr);
    // 5) chunked scan: 8192 waves, depth-4 register prefetch
    scan_phase1<<<2048, 256, 0, stream>>>(PROJ, XSb, alog, APROD, HFIN);
    scan_phase2<<<256, 256, 0, stream>>>(h0, APROD, HFIN, hout);
    scan_phase3<<<2048, 256, 0, stream>>>(PROJ, XSb, ZG, alog, dv, HFIN, YG);
    // 6) out = x + yg @ W_out^T
    gemm_bt<2><<<dim3(32, 16), 128, 0, stream>>>(YG, W3, out, nullptr, x);

    (void)in_sizes; (void)n_in; (void)out_size; (void)ws_size;
}

// Round 8
// 538.388 us; speedup vs baseline: 1.1042x; 1.1042x over previous
//
#include <hip/hip_runtime.h>
#include <cstdint>
#include <cstddef>

// ---------------------------------------------------------------------------
// JambaMambaBlock on MI355X (gfx950)
// Pipeline: rmsnorm -> GEMM1(in_proj, split epilogue: x fp32 / silu(z) bf16)
//           -> depthwise conv+silu -> GEMM2(x_proj, softplus epilogue)
//           -> chunked SSM scan (3 phases) -> GEMM3(out_proj, +residual)
//
// GEMMs (round 8): barrier-free direct-global K-loop on fragment-linear
// operands; 256-thr blocks, block tile 128x256, wave tile 64x128.
// __launch_bounds__(256, 2) -> VGPR cap 256 (fits acc128+frags96+addr ~236;
// round 7's cap of 160 spilled acc and collapsed MfmaUtil to 12%).
// Producers write swizzled layout with coalesced stores.
// Scan: 32 chunks of 64 steps; 4 lanes per d-channel; depth-4 reg prefetch.
// ---------------------------------------------------------------------------

typedef __bf16 bf16_t;
typedef __attribute__((ext_vector_type(8))) __bf16 bf16x8;
typedef __attribute__((ext_vector_type(4))) __bf16 bf16x4;
typedef __attribute__((ext_vector_type(4))) float f32x4;

#define D_MODEL 2048
#define D_STATE 16
#define B_SZ 2
#define T_LEN 2048
#define N_ROWS (B_SZ * T_LEN)        // 4096
#define N_PAD2 2304                  // x_proj rows padded 2080 -> 9*256
#define P_PITCH 2304                 // PROJ row pitch
#define N_CHUNK 32
#define L_CHUNK (T_LEN / N_CHUNK)    // 64
#define LOG2E 1.4426950408889634f
#define KT 64                        // K=2048 -> 64 k-tiles everywhere
#define PANEL 32768                  // 64 tiles * 512 elems per 16-row panel

// ---------------- fused weight cast + swizzle ----------------
// tiles: W1 16384 | W2 9216 (rows >=2080 zero) | W3 8192; one wave per tile
__global__ __launch_bounds__(256) void cast_weights(
    const float* __restrict__ w_in, const float* __restrict__ w_x,
    const float* __restrict__ w_out,
    bf16_t* __restrict__ W1s, bf16_t* __restrict__ W2s, bf16_t* __restrict__ W3s)
{
    int wv   = blockIdx.x * 4 + (threadIdx.x >> 6);
    int lane = threadIdx.x & 63;
    const float* src; bf16_t* dst; int nrows; int tile;
    if (wv < 16384)      { src = w_in;  dst = W1s; tile = wv;         nrows = 4096; }
    else if (wv < 25600) { src = w_x;   dst = W2s; tile = wv - 16384; nrows = 2080; }
    else                 { src = w_out; dst = W3s; tile = wv - 25600; nrows = 2048; }
    int r16 = tile >> 6, kt = tile & 63;
    int row = r16 * 16 + (lane & 15);
    int k0  = kt * 32 + (lane >> 4) * 8;
    f32x4 v0 = {0.f, 0.f, 0.f, 0.f}, v1 = v0;
    if (row < nrows) {
        v0 = *(const f32x4*)&src[(size_t)row * 2048 + k0];
        v1 = *(const f32x4*)&src[(size_t)row * 2048 + k0 + 4];
    }
    bf16x4 lo = __builtin_convertvector(v0, bf16x4);
    bf16x4 hi = __builtin_convertvector(v1, bf16x4);
    bf16x8 o;
    #pragma unroll
    for (int e = 0; e < 4; ++e) { o[e] = lo[e]; o[e + 4] = hi[e]; }
    *(bf16x8*)(dst + (size_t)tile * 512 + lane * 8) = o;
}

// ---------------- rmsnorm -> swizzled bf16 (LDS-staged) ----------------
__global__ __launch_bounds__(256) void rmsnorm_swz(
    const float* __restrict__ x, const float* __restrict__ w,
    bf16_t* __restrict__ xn)
{
    __shared__ bf16_t st[16][2056];           // +8 pad breaks bank stride
    int r16 = blockIdx.x;                     // 0..255
    int tid = threadIdx.x;
    int wave = tid >> 6, lane = tid & 63;

    f32x4 wv[8];
    #pragma unroll
    for (int c = 0; c < 8; ++c) wv[c] = *(const f32x4*)&w[(c * 64 + lane) * 4];

    for (int rr = 0; rr < 4; ++rr) {
        int row = r16 * 16 + wave * 4 + rr;
        const float* xr = x + (size_t)row * 2048;
        f32x4 vv[8];
        float ss = 0.f;
        #pragma unroll
        for (int c = 0; c < 8; ++c) {
            vv[c] = *(const f32x4*)&xr[(c * 64 + lane) * 4];
            ss += vv[c][0]*vv[c][0] + vv[c][1]*vv[c][1]
                + vv[c][2]*vv[c][2] + vv[c][3]*vv[c][3];
        }
        #pragma unroll
        for (int o = 32; o > 0; o >>= 1) ss += __shfl_down(ss, o, 64);
        float s = __shfl(ss, 0, 64);
        s = rsqrtf(s * (1.f / 2048.f) + 1e-6f);
        #pragma unroll
        for (int c = 0; c < 8; ++c) {
            bf16x4 o4;
            #pragma unroll
            for (int e = 0; e < 4; ++e) o4[e] = (bf16_t)(vv[c][e] * s * wv[c][e]);
            *(bf16x4*)&st[wave * 4 + rr][(c * 64 + lane) * 4] = o4;
        }
    }
    __syncthreads();
    const size_t base = (size_t)r16 * PANEL;
    #pragma unroll
    for (int c = 0; c < 16; ++c) {
        int f  = (c * 256 + tid) * 8;         // swizzled flat element offset
        int kt = f >> 9;
        int off3 = (f & 511) >> 3;            // m + 16*q
        int m = off3 & 15, q = off3 >> 4;
        bf16x8 v = *(const bf16x8*)&st[m][kt * 32 + q * 8];
        *(bf16x8*)(xn + base + f) = v;
    }
}

// ---------------- bf16 GEMM: C[M,N] = A @ B^T, fragment-direct ----------
// 256 threads = 4 waves; block tile 128x256; wave tile 64x128.
// wave&1 -> M half; wave>>1 -> N half. K = 2048 (KT=64).
// MODE 0 (GEMM1): bn<8 -> out0 fp32 ldc 2048; bn>=8 -> out1 bf16 silu
// MODE 1 (GEMM2): out0 fp32 ldc P_PITCH; softplus when bn<8
// MODE 2 (GEMM3): out0 = v + add, fp32 ldc 2048
template<int MODE>
__global__ __launch_bounds__(256, 2) void gemm_bt(
    const bf16_t* __restrict__ A, const bf16_t* __restrict__ B,
    float* __restrict__ out0, bf16_t* __restrict__ out1,
    const float* __restrict__ add)
{
    __shared__ __align__(16) float cs[4][16 * 132];   // per-wave epilogue strip
    const int tid = threadIdx.x;
    const int bm = blockIdx.x, bn = blockIdx.y;
    const int lane = tid & 63;
    const int wave = tid >> 6;
    const int fr = lane & 15;
    const int quad = lane >> 4;

    const bf16_t* aB = A + (((size_t)(bm * 8 + (wave & 1) * 4) * KT) << 9) + lane * 8;
    const bf16_t* bB = B + (((size_t)(bn * 16 + (wave >> 1) * 8) * KT) << 9) + lane * 8;

    f32x4 acc[4][8];
    #pragma unroll
    for (int i = 0; i < 4; ++i)
        #pragma unroll
        for (int j = 0; j < 8; ++j) acc[i][j] = {0.f, 0.f, 0.f, 0.f};

    bf16x8 aC[4], bC[8];
    #pragma unroll
    for (int i = 0; i < 4; ++i) aC[i] = *(const bf16x8*)(aB + (size_t)i * PANEL);
    #pragma unroll
    for (int j = 0; j < 8; ++j) bC[j] = *(const bf16x8*)(bB + (size_t)j * PANEL);

    #pragma unroll 2
    for (int kt = 0; kt < KT; ++kt) {
        const int ktn = (kt < KT - 1) ? (kt + 1) : (KT - 1);
        bf16x8 aN[4], bN[8];
        #pragma unroll
        for (int i = 0; i < 4; ++i)
            aN[i] = *(const bf16x8*)(aB + (size_t)i * PANEL + ((size_t)ktn << 9));
        #pragma unroll
        for (int j = 0; j < 8; ++j)
            bN[j] = *(const bf16x8*)(bB + (size_t)j * PANEL + ((size_t)ktn << 9));
        #pragma unroll
        for (int i = 0; i < 4; ++i)
            #pragma unroll
            for (int j = 0; j < 8; ++j)
                acc[i][j] = __builtin_amdgcn_mfma_f32_16x16x32_bf16(
                    aC[i], bC[j], acc[i][j], 0, 0, 0);
        #pragma unroll
        for (int i = 0; i < 4; ++i) aC[i] = aN[i];
        #pragma unroll
        for (int j = 0; j < 8; ++j) bC[j] = bN[j];
    }

    // ---- per-wave LDS strip epilogue (no cross-wave barrier needed) ----
    float* csw = cs[wave];
    for (int i = 0; i < 4; ++i) {              // 16-row strips
        #pragma unroll
        for (int j = 0; j < 8; ++j)
            #pragma unroll
            for (int rr = 0; rr < 4; ++rr)
                csw[(quad * 4 + rr) * 132 + j * 16 + fr] = acc[i][j][rr];
        #pragma unroll
        for (int s = 0; s < 8; ++s) {
            int t   = lane + s * 64;           // 0..511 f32x4 chunks
            int row = t >> 5;
            int c4  = (t & 31) * 4;
            f32x4 v = *(const f32x4*)&csw[row * 132 + c4];
            int gr = bm * 128 + (wave & 1) * 64 + i * 16 + row;
            int gc = bn * 256 + (wave >> 1) * 128 + c4;
            if (MODE == 0) {
                if (bn < 8) {
                    *(f32x4*)&out0[(size_t)gr * 2048 + gc] = v;
                } else {
                    bf16x4 o;
                    #pragma unroll
                    for (int e = 0; e < 4; ++e) {
                        float sv = v[e];
                        o[e] = (bf16_t)(sv / (1.f + __expf(-sv)));
                    }
                    *(bf16x4*)&out1[(size_t)gr * 2048 + (gc - 2048)] = o;
                }
            } else if (MODE == 1) {
                if (bn < 8) {
                    #pragma unroll
                    for (int e = 0; e < 4; ++e) {
                        float sv = v[e];
                        v[e] = fmaxf(sv, 0.f) + __logf(1.f + __expf(-fabsf(sv)));
                    }
                }
                *(f32x4*)&out0[(size_t)gr * P_PITCH + gc] = v;
            } else {
                f32x4 a4 = *(const f32x4*)&add[(size_t)gr * 2048 + gc];
                v = v + a4;
                *(f32x4*)&out0[(size_t)gr * 2048 + gc] = v;
            }
        }
    }
}

// ---------------- depthwise causal conv(4) + silu -> swizzled bf16 --------
// wave-per-tile: each wave emits one complete 1KB tile (16 t x 32 d) with a
// single fully-coalesced 16B/lane store.
__global__ __launch_bounds__(256) void conv_silu_swz(
    const float* __restrict__ xb, const float* __restrict__ cw,
    const float* __restrict__ cb, bf16_t* __restrict__ xs_s)
{
    int tile = blockIdx.x * 4 + (threadIdx.x >> 6);   // 0..16383
    int lane = threadIdx.x & 63;
    int r16  = tile >> 6;                // 16-row group (0..255)
    int dt   = tile & 63;                // d-tile
    int m    = lane & 15;
    int d0   = dt * 32 + (lane >> 4) * 8;
    int row  = r16 * 16 + m;
    int t    = row & 2047;               // t within batch

    float a[8];
    {
        f32x4 b0 = *(const f32x4*)&cb[d0], b1 = *(const f32x4*)&cb[d0 + 4];
        #pragma unroll
        for (int e = 0; e < 4; ++e) { a[e] = b0[e]; a[4 + e] = b1[e]; }
    }
    f32x4 cwv[8];
    #pragma unroll
    for (int e = 0; e < 8; ++e) cwv[e] = *(const f32x4*)&cw[(d0 + e) * 4];

    #pragma unroll
    for (int tap = 0; tap < 4; ++tap) {
        int tr = t - 3 + tap;
        if (tr >= 0) {
            const float* xr = xb + ((size_t)(row - 3 + tap)) * 2048 + d0;
            f32x4 x0 = *(const f32x4*)xr, x1 = *(const f32x4*)(xr + 4);
            #pragma unroll
            for (int e = 0; e < 4; ++e) {
                a[e]     = fmaf(cwv[e][tap],     x0[e], a[e]);
                a[4 + e] = fmaf(cwv[4 + e][tap], x1[e], a[4 + e]);
            }
        }
    }
    bf16x8 o;
    #pragma unroll
    for (int e = 0; e < 8; ++e) {
        float s = a[e];
        o[e] = (bf16_t)(s / (1.f + __expf(-s)));
    }
    *(bf16x8*)(xs_s + (size_t)tile * 512 + lane * 8) = o;
}

// ---------------- chunked SSM scan ----------------
// Wave wi in [0,8192): c = wi&31, dg = (wi>>5)&127, b = wi>>12.
// Lane: nq = lane&3 (state quad), dsub = lane>>2; dd = dg*16 + dsub.
// xs is fragment-swizzled bf16; proj is row-major fp32 (da|B|C), pitch 2304.
#define PF 4   // prefetch depth

__device__ __forceinline__ size_t xs_off(int row, int ddo) {
    return ((size_t)(row >> 4) << 15) + (size_t)((row & 15) << 3) + ddo;
}

// phase 1: local scan with zero init; store decay product + local final state
__global__ __launch_bounds__(256) void scan_phase1(
    const float* __restrict__ proj, const bf16_t* __restrict__ xs,
    const float* __restrict__ A_log,
    float* __restrict__ Aprod, float* __restrict__ hfin)
{
    int wi   = blockIdx.x * 4 + (threadIdx.x >> 6);
    int lane = threadIdx.x & 63;
    int nq   = lane & 3;
    int dsub = lane >> 2;
    int c  = wi & 31;
    int dg = (wi >> 5) & 127;
    int b  = wi >> 12;
    int dd = dg * 16 + dsub;
    const int ddo = ((dd >> 5) << 9) + (((dd & 31) >> 3) << 7) + (dd & 7);

    float A2[4], h[4], Ap[4];
    #pragma unroll
    for (int j = 0; j < 4; ++j) {
        A2[j] = -__expf(A_log[dd * D_STATE + nq * 4 + j]) * LOG2E;
        h[j] = 0.f; Ap[j] = 1.f;
    }
    const int t0 = c * L_CHUNK;
    const int tmax = t0 + L_CHUNK - 1;

    float p_da[PF], p_xv[PF];
    f32x4 p_B[PF];
    #pragma unroll
    for (int u = 0; u < PF; ++u) {
        int row = b * T_LEN + t0 + u;
        const float* pr = proj + (size_t)row * P_PITCH;
        p_da[u] = pr[dd];
        p_xv[u] = (float)xs[xs_off(row, ddo)];
        p_B[u]  = *(const f32x4*)(pr + D_MODEL + nq * 4);
    }

    for (int it = 0; it < L_CHUNK; it += PF) {
        #pragma unroll
        for (int u = 0; u < PF; ++u) {
            int t = t0 + it + u;
            float da = p_da[u], xv = p_xv[u];
            f32x4 Bv = p_B[u];
            int tn = t + PF; tn = (tn > tmax) ? tmax : tn;
            {
                int row = b * T_LEN + tn;
                const float* pr = proj + (size_t)row * P_PITCH;
                p_da[u] = pr[dd];
                p_xv[u] = (float)xs[xs_off(row, ddo)];
                p_B[u]  = *(const f32x4*)(pr + D_MODEL + nq * 4);
            }
            float dx = da * xv;
            #pragma unroll
            for (int j = 0; j < 4; ++j) {
                float a = exp2f(da * A2[j]);
                Ap[j] *= a;
                h[j] = fmaf(a, h[j], dx * Bv[j]);
            }
        }
    }
    size_t o = ((size_t)c * 4096 + b * 2048 + dd) * D_STATE + nq * 4;
    *(f32x4*)(Aprod + o) = f32x4{Ap[0], Ap[1], Ap[2], Ap[3]};
    *(f32x4*)(hfin  + o) = f32x4{h[0], h[1], h[2], h[3]};
}

// phase 2: serial combine across chunks; hfin -> h_init in place; h_out exact
__global__ __launch_bounds__(256) void scan_phase2(
    const float* __restrict__ h_in, const float* __restrict__ Aprod,
    float* __restrict__ hfin, float* __restrict__ h_out)
{
    int g = blockIdx.x * 256 + threadIdx.x;
    float h = h_in[g];
    for (int c = 0; c < N_CHUNK; ++c) {
        size_t o = (size_t)c * 65536 + g;
        float a   = Aprod[o];
        float loc = hfin[o];
        hfin[o] = h;
        h = fmaf(a, h, loc);
    }
    h_out[g] = h;
}

// phase 3: replay from exact initial state; emit gated y (swizzled bf16)
__global__ __launch_bounds__(256) void scan_phase3(
    const float* __restrict__ proj, const bf16_t* __restrict__ xs,
    const bf16_t* __restrict__ zg, const float* __restrict__ A_log,
    const float* __restrict__ Dv, const float* __restrict__ hinit,
    bf16_t* __restrict__ yg)
{
    int wi   = blockIdx.x * 4 + (threadIdx.x >> 6);
    int lane = threadIdx.x & 63;
    int nq   = lane & 3;
    int dsub = lane >> 2;
    int c  = wi & 31;
    int dg = (wi >> 5) & 127;
    int b  = wi >> 12;
    int dd = dg * 16 + dsub;
    const int ddo = ((dd >> 5) << 9) + (((dd & 31) >> 3) << 7) + (dd & 7);

    float A2[4], h[4];
    size_t o = ((size_t)c * 4096 + b * 2048 + dd) * D_STATE + nq * 4;
    #pragma unroll
    for (int j = 0; j < 4; ++j) {
        A2[j] = -__expf(A_log[dd * D_STATE + nq * 4 + j]) * LOG2E;
        h[j]  = hinit[o + j];
    }
    float Dd = Dv[dd];
    const int t0 = c * L_CHUNK;
    const int tmax = t0 + L_CHUNK - 1;

    float p_da[PF], p_xv[PF], p_sz[PF];
    f32x4 p_B[PF], p_C[PF];
    #pragma unroll
    for (int u = 0; u < PF; ++u) {
        int row = b * T_LEN + t0 + u;
        const float* pr = proj + (size_t)row * P_PITCH;
        p_da[u] = pr[dd];
        p_xv[u] = (float)xs[xs_off(row, ddo)];
        p_sz[u] = (float)zg[(size_t)row * 2048 + dd];
        p_B[u]  = *(const f32x4*)(pr + D_MODEL + nq * 4);
        p_C[u]  = *(const f32x4*)(pr + D_MODEL + D_STATE + nq * 4);
    }

    for (int it = 0; it < L_CHUNK; it += PF) {
        #pragma unroll
        for (int u = 0; u < PF; ++u) {
            int t = t0 + it + u;
            float da = p_da[u], xv = p_xv[u], sz = p_sz[u];
            f32x4 Bv = p_B[u], Cv = p_C[u];
            int tn = t + PF; tn = (tn > tmax) ? tmax : tn;
            {
                int row = b * T_LEN + tn;
                const float* pr = proj + (size_t)row * P_PITCH;
                p_da[u] = pr[dd];
                p_xv[u] = (float)xs[xs_off(row, ddo)];
                p_sz[u] = (float)zg[(size_t)row * 2048 + dd];
                p_B[u]  = *(const f32x4*)(pr + D_MODEL + nq * 4);
                p_C[u]  = *(const f32x4*)(pr + D_MODEL + D_STATE + nq * 4);
            }
            float dx = da * xv;
            float yp = 0.f;
            #pragma unroll
            for (int j = 0; j < 4; ++j) {
                float a = exp2f(da * A2[j]);
                h[j] = fmaf(a, h[j], dx * Bv[j]);
                yp = fmaf(h[j], Cv[j], yp);
            }
            yp += __shfl_xor(yp, 1, 64);
            yp += __shfl_xor(yp, 2, 64);
            if (nq == 0) {
                float y = fmaf(Dd, xv, yp);
                int row = b * T_LEN + t;
                yg[xs_off(row, ddo)] = (bf16_t)(y * sz);
            }
        }
    }
}

// ---------------------------------------------------------------------------
extern "C" void kernel_launch(void* const* d_in, const int* in_sizes, int n_in,
                              void* d_out, int out_size, void* d_ws, size_t ws_size,
                              hipStream_t stream)
{
    const float* x    = (const float*)d_in[0];
    const float* h0   = (const float*)d_in[1];
    const float* nw   = (const float*)d_in[2];
    const float* w_in = (const float*)d_in[3];
    const float* cw   = (const float*)d_in[4];
    const float* cb   = (const float*)d_in[5];
    const float* w_x  = (const float*)d_in[6];
    const float* alog = (const float*)d_in[7];
    const float* dv   = (const float*)d_in[8];
    const float* w_out= (const float*)d_in[9];
    float* out  = (float*)d_out;
    float* hout = out + (size_t)N_ROWS * D_MODEL;

    char* ws = (char*)d_ws;
    size_t off = 0;
    auto alloc = [&](size_t bytes) -> void* {
        void* p = ws + off;
        off += (bytes + 255) & ~(size_t)255;
        return p;
    };
    bf16_t* W1  = (bf16_t*)alloc((size_t)16384 * 512 * 2);   // in_proj swizzled
    bf16_t* W2  = (bf16_t*)alloc((size_t)9216 * 512 * 2);    // x_proj swizzled+pad
    bf16_t* W3  = (bf16_t*)alloc((size_t)8192 * 512 * 2);    // out_proj swizzled
    bf16_t* XN  = (bf16_t*)alloc((size_t)N_ROWS * 2048 * 2); // normed x, swizzled
    float*  XB  = (float*) alloc((size_t)N_ROWS * 2048 * 4); // x-branch fp32 rm
    bf16_t* ZG  = (bf16_t*)alloc((size_t)N_ROWS * 2048 * 2); // silu(z) bf16 rm
    float*  PROJ= (float*) alloc((size_t)N_ROWS * P_PITCH * 4);// da|B|C fp32 rm
    float* APROD= (float*) alloc((size_t)N_CHUNK * 4096 * D_STATE * 4);
    float* HFIN = (float*) alloc((size_t)N_CHUNK * 4096 * D_STATE * 4);
    // aliases (lifetimes disjoint in stream order):
    bf16_t* XSb = W1;   // conv out, swizzled (W1 dead after GEMM1; lives thru scan)
    bf16_t* YG  = XN;   // gated y, swizzled  (XN dead after GEMM1)

    // weight casts + swizzle (33792 tiles, 4 waves/block)
    cast_weights<<<8448, 256, 0, stream>>>(w_in, w_x, w_out, W1, W2, W3);

    // 1) rmsnorm -> swizzled XN (LDS-staged coalesced)
    rmsnorm_swz<<<256, 256, 0, stream>>>(x, nw, XN);
    // 2) xz = xn @ W_in^T; epilogue splits x fp32 / silu(z) bf16
    gemm_bt<0><<<dim3(32, 16), 256, 0, stream>>>(XN, W1, XB, ZG, nullptr);
    // 3) conv + silu -> swizzled bf16 (wave-per-tile, coalesced stores)
    conv_silu_swz<<<4096, 256, 0, stream>>>(XB, cw, cb, XSb);
    // 4) proj = xssm @ W_x^T; epilogue applies softplus to delta cols
    gemm_bt<1><<<dim3(32, 9), 256, 0, stream>>>(XSb, W2, PROJ, nullptr, nullptr);
    // 5) chunked scan: 8192 waves, depth-4 register prefetch
    scan_phase1<<<2048, 256, 0, stream>>>(PROJ, XSb, alog, APROD, HFIN);
    scan_phase2<<<256, 256, 0, stream>>>(h0, APROD, HFIN, hout);
    scan_phase3<<<2048, 256, 0, stream>>>(PROJ, XSb, ZG, alog, dv, HFIN, YG);
    // 6) out = x + yg @ W_out^T
    gemm_bt<2><<<dim3(32, 8), 256, 0, stream>>>(YG, W3, out, nullptr, x);

    (void)in_sizes; (void)n_in; (void)out_size; (void)ws_size;
}